// Round 3
// baseline (191.043 us; speedup 1.0000x reference)
//
#include <hip/hip_runtime.h>
#include <hip/hip_bf16.h>
#include <stdint.h>

#define HEAD 64
#define CEMB 1024
#define BB 8
#define TSEQ 2048

typedef __attribute__((ext_vector_type(8))) short bf16x8;
typedef __attribute__((ext_vector_type(4))) float f32x4;

__device__ __forceinline__ unsigned short f2bf(float f) {
    union { float f; uint32_t u; } c; c.f = f;
    uint32_t u = c.u + 0x7FFF + ((c.u >> 16) & 1);
    return (unsigned short)(u >> 16);
}
__device__ __forceinline__ ushort4 f4bf(float4 v) {
    ushort4 u; u.x = f2bf(v.x); u.y = f2bf(v.y); u.z = f2bf(v.z); u.w = f2bf(v.w);
    return u;
}

// ---------------- Kernel 0: W -> WT bf16 [192][1024] via LDS transpose -------
__global__ __launch_bounds__(256) void prep_w(
        const float* __restrict__ Wk, const float* __restrict__ bk,
        const float* __restrict__ Wq, const float* __restrict__ bq,
        const float* __restrict__ Wv, const float* __restrict__ bv,
        unsigned short* __restrict__ WT, float* __restrict__ biasb) {
    __shared__ float Ws[64][68];
    const int p = blockIdx.x >> 4, kc = blockIdx.x & 15;
    const float* W  = (p == 0) ? Wk : (p == 1) ? Wq : Wv;
    const float* bi = (p == 0) ? bk : (p == 1) ? bq : bv;
    const float scale = (p == 1) ? 0.03125f : 1.0f;   // fold C^-0.5 into q
    const int tid = threadIdx.x;
    const int h4 = (tid & 15) * 4;
    for (int r = 0; r < 4; r++) {
        int kl = (tid >> 4) + r * 16;
        float4 v = *(const float4*)(W + (long)(kc * 64 + kl) * 64 + h4);
        *(float4*)(&Ws[kl][h4]) = v;
    }
    __syncthreads();
    const int h = tid >> 2, k0 = (tid & 3) * 16;
    unsigned short ov[16];
    for (int i = 0; i < 16; i++) ov[i] = f2bf(Ws[k0 + i][h] * scale);
    unsigned short* dst = WT + (long)(p * 64 + h) * CEMB + kc * 64 + k0;
    *(int4*)(dst)     = *(int4*)(ov);
    *(int4*)(dst + 8) = *((int4*)(ov) + 1);
    if (kc == 0 && tid < 64) biasb[p * 64 + tid] = bi[tid] * scale;
}

// ---------------- Kernel 1: projections  [16384 x 1024] @ [1024 x 192] -------
// grid 512 x 256thr. Block = 32 rows. A staged ONCE in LDS (1 barrier total);
// B streamed straight from global (L2-hot 384 KB). Zero barriers in K-loop.
__global__ __launch_bounds__(256) void proj_gemm(
        const float* __restrict__ x, const unsigned short* __restrict__ WT,
        const float* __restrict__ biasb,
        unsigned short* __restrict__ Kb, unsigned short* __restrict__ Qb,
        unsigned short* __restrict__ VTb) {
    __shared__ __align__(16) unsigned short As[32 * 1032];   // stride 1032 bf16

    const int tid = threadIdx.x;
    const int lane = tid & 63, w = tid >> 6;
    const int l15 = lane & 15, q4 = lane >> 4;
    const int mw = w & 1, nw = w >> 1;            // 2 m-tiles x 2 n-halves
    const long rowbase = (long)blockIdx.x * 32;

    // ---- phase 1: stage x[32][1024] -> bf16 LDS (coalesced 128B bursts) ----
    {
        const int r = tid >> 3, c8 = tid & 7;
        const float* xr = x + (rowbase + r) * CEMB + c8 * 4;
        unsigned short* lr = As + r * 1032 + c8 * 4;
        #pragma unroll
        for (int i = 0; i < 32; i += 4) {
            float4 v0 = *(const float4*)(xr + (i + 0) * 32);
            float4 v1 = *(const float4*)(xr + (i + 1) * 32);
            float4 v2 = *(const float4*)(xr + (i + 2) * 32);
            float4 v3 = *(const float4*)(xr + (i + 3) * 32);
            *(ushort4*)(lr + (i + 0) * 32) = f4bf(v0);
            *(ushort4*)(lr + (i + 1) * 32) = f4bf(v1);
            *(ushort4*)(lr + (i + 2) * 32) = f4bf(v2);
            *(ushort4*)(lr + (i + 3) * 32) = f4bf(v3);
        }
    }
    __syncthreads();

    // ---- phase 2: K-loop, no barriers ----
    f32x4 z = {0.f, 0.f, 0.f, 0.f};
    f32x4 acc[6];
    for (int j = 0; j < 6; j++) acc[j] = z;

    const unsigned short* Am = As + (mw * 16 + l15) * 1032 + q4 * 8;
    const unsigned short* Bg = WT + (long)(nw * 96 + l15) * CEMB + q4 * 8;

    #pragma unroll 4
    for (int kc = 0; kc < 32; kc++) {
        bf16x8 a = *(const bf16x8*)(Am + kc * 32);
        bf16x8 bfr[6];
        #pragma unroll
        for (int j = 0; j < 6; j++)
            bfr[j] = *(const bf16x8*)(Bg + (long)j * 16 * CEMB + kc * 32);
        #pragma unroll
        for (int j = 0; j < 6; j++)
            acc[j] = __builtin_amdgcn_mfma_f32_16x16x32_bf16(a, bfr[j], acc[j], 0, 0, 0);
    }

    // ---- epilogue: +bias, cast bf16, scatter to K / Q / VT ----
    for (int j = 0; j < 6; j++) {
        const int n = nw * 96 + j * 16 + l15;
        const float bias = biasb[n];
        const long row0 = rowbase + mw * 16 + q4 * 4;
        if (n < 128) {
            unsigned short* dst = (n < 64) ? (Kb + row0 * HEAD + n)
                                           : (Qb + row0 * HEAD + (n - 64));
            for (int r = 0; r < 4; r++)
                dst[r * HEAD] = f2bf(acc[j][r] + bias);
        } else {
            const int h = n - 128;
            const long b = row0 >> 11; const int t = (int)(row0 & 2047);
            ushort4 pk;
            pk.x = f2bf(acc[j][0] + bias);
            pk.y = f2bf(acc[j][1] + bias);
            pk.z = f2bf(acc[j][2] + bias);
            pk.w = f2bf(acc[j][3] + bias);
            *(ushort4*)(VTb + b * (HEAD * (long)TSEQ) + (long)h * TSEQ + t) = pk;
        }
    }
}

// ---------------- Kernel 2: causal softplus-attention, 32-row t-tiles --------
// grid 512 = (64 t-tiles x 8 b), largest tile first. 4 waves split s-chunks.
__global__ __launch_bounds__(256) void attn(
        const unsigned short* __restrict__ Kb, const unsigned short* __restrict__ Qb,
        const unsigned short* __restrict__ VTb, float* __restrict__ out) {
    __shared__ __align__(16) unsigned short Pl[4][2][32 * 40];  // wave, dbuf, [t32][s pad40]
    __shared__ __align__(16) float red[3][64 * 36];

    const int tid = threadIdx.x;
    const int lane = tid & 63, w = tid >> 6;
    const int l15 = lane & 15, q4 = lane >> 4;

    const int bid = blockIdx.x;
    const int ti = 63 - (bid >> 3);             // largest t-tile first
    const int b = bid & 7;
    const int t0 = ti * 32;

    const unsigned short* kb  = Kb  + (long)b * TSEQ * HEAD;
    const unsigned short* qb  = Qb  + (long)b * TSEQ * HEAD;
    const unsigned short* vtb = VTb + (long)b * HEAD * TSEQ;

    // K fragments (fixed per block): B-operand, n = t-local, k = h
    bf16x8 kf[2][2];
    for (int tt = 0; tt < 2; tt++)
        for (int kk = 0; kk < 2; kk++)
            kf[tt][kk] = *(const bf16x8*)(kb + (t0 + tt * 16 + l15) * HEAD + kk * 32 + q4 * 8);

    f32x4 z = {0.f, 0.f, 0.f, 0.f};
    f32x4 oacc[4][2];
    for (int hh = 0; hh < 4; hh++) for (int tt = 0; tt < 2; tt++) oacc[hh][tt] = z;

    int buf = 0;
    for (int c = w; c <= ti; c += 4) {
        const int s0 = c * 32;
        unsigned short* myP = &Pl[w][buf][0];

        // S^T = Q K^T: 2 s-tiles x 2 t-tiles
        f32x4 sc[2][2];
        for (int st2 = 0; st2 < 2; st2++) {
            bf16x8 qf0 = *(const bf16x8*)(qb + (s0 + st2 * 16 + l15) * HEAD + q4 * 8);
            bf16x8 qf1 = *(const bf16x8*)(qb + (s0 + st2 * 16 + l15) * HEAD + 32 + q4 * 8);
            for (int tt = 0; tt < 2; tt++) {
                f32x4 s = z;
                s = __builtin_amdgcn_mfma_f32_16x16x32_bf16(qf0, kf[tt][0], s, 0, 0, 0);
                s = __builtin_amdgcn_mfma_f32_16x16x32_bf16(qf1, kf[tt][1], s, 0, 0, 0);
                sc[st2][tt] = s;
            }
        }
        // softplus + causal mask; pack bf16 -> P^T LDS [t-local][s-local]
        for (int tt = 0; tt < 2; tt++) {
            const int tg = t0 + tt * 16 + l15;
            for (int st2 = 0; st2 < 2; st2++) {
                ushort4 pk;
                unsigned short pv[4];
                for (int r = 0; r < 4; r++) {
                    int sg = s0 + st2 * 16 + q4 * 4 + r;
                    float p = __logf(1.0f + __expf(sc[st2][tt][r]));
                    if (sg > tg) p = 0.0f;
                    pv[r] = f2bf(p);
                }
                pk.x = pv[0]; pk.y = pv[1]; pk.z = pv[2]; pk.w = pv[3];
                *(ushort4*)(myP + (tt * 16 + l15) * 40 + st2 * 16 + q4 * 4) = pk;
            }
        }
        __threadfence_block();
        // P^T as B-operand: n = t-local, k = s-local (0..31)
        bf16x8 pf0 = *(const bf16x8*)(myP + l15 * 40 + q4 * 8);
        bf16x8 pf1 = *(const bf16x8*)(myP + (16 + l15) * 40 + q4 * 8);
        // O^T += V^T @ P^T
        for (int hh = 0; hh < 4; hh++) {
            bf16x8 vf = *(const bf16x8*)(vtb + (hh * 16 + l15) * (long)TSEQ + s0 + q4 * 8);
            oacc[hh][0] = __builtin_amdgcn_mfma_f32_16x16x32_bf16(vf, pf0, oacc[hh][0], 0, 0, 0);
            oacc[hh][1] = __builtin_amdgcn_mfma_f32_16x16x32_bf16(vf, pf1, oacc[hh][1], 0, 0, 0);
        }
        buf ^= 1;
    }

    // cross-wave reduction of O^T partials
    if (w > 0) {
        float* r0 = &red[w - 1][lane * 36];
        for (int hh = 0; hh < 4; hh++)
            for (int tt = 0; tt < 2; tt++)
                *(f32x4*)(r0 + (hh * 2 + tt) * 4) = oacc[hh][tt];
    }
    __syncthreads();
    if (w == 0) {
        for (int i = 0; i < 3; i++) {
            const float* r0 = &red[i][lane * 36];
            for (int hh = 0; hh < 4; hh++)
                for (int tt = 0; tt < 2; tt++)
                    oacc[hh][tt] += *(const f32x4*)(r0 + (hh * 2 + tt) * 4);
        }
        for (int tt = 0; tt < 2; tt++) {
            float* ob = out + ((long)b * TSEQ + t0 + tt * 16 + l15) * HEAD + q4 * 4;
            for (int hh = 0; hh < 4; hh++)
                *(f32x4*)(ob + hh * 16) = oacc[hh][tt];
        }
    }
}

// ---------------- host launch ------------------------------------------------
extern "C" void kernel_launch(void* const* d_in, const int* in_sizes, int n_in,
                              void* d_out, int out_size, void* d_ws, size_t ws_size,
                              hipStream_t stream) {
    const float* x  = (const float*)d_in[0];
    const float* Wk = (const float*)d_in[1];
    const float* bk = (const float*)d_in[2];
    const float* Wq = (const float*)d_in[3];
    const float* bq = (const float*)d_in[4];
    const float* Wv = (const float*)d_in[5];
    const float* bv = (const float*)d_in[6];
    float* out = (float*)d_out;

    char* ws = (char*)d_ws;
    unsigned short* WT    = (unsigned short*)(ws);                      // 384 KB
    float*          biasb = (float*)(ws + 393216);                      // 768 B
    unsigned short* Kb    = (unsigned short*)(ws + 524288);             // 2 MB
    unsigned short* Qb    = (unsigned short*)(ws + 524288 + 2097152);   // 2 MB
    unsigned short* VTb   = (unsigned short*)(ws + 524288 + 4194304);   // 2 MB

    prep_w<<<48, 256, 0, stream>>>(Wk, bk, Wq, bq, Wv, bv, WT, biasb);
    proj_gemm<<<512, 256, 0, stream>>>(x, WT, biasb, Kb, Qb, VTb);
    attn<<<512, 256, 0, stream>>>(Kb, Qb, VTb, out);
}

// Round 4
// 153.449 us; speedup vs baseline: 1.2450x; 1.2450x over previous
//
#include <hip/hip_runtime.h>
#include <hip/hip_bf16.h>
#include <stdint.h>

#define HEAD 64
#define CEMB 1024
#define BB 8
#define TSEQ 2048

typedef __attribute__((ext_vector_type(8))) short bf16x8;
typedef __attribute__((ext_vector_type(4))) float f32x4;

__device__ __forceinline__ unsigned short f2bf(float f) {
    union { float f; uint32_t u; } c; c.f = f;
    uint32_t u = c.u + 0x7FFF + ((c.u >> 16) & 1);
    return (unsigned short)(u >> 16);
}
__device__ __forceinline__ ushort4 f4bf(float4 v) {
    ushort4 u; u.x = f2bf(v.x); u.y = f2bf(v.y); u.z = f2bf(v.z); u.w = f2bf(v.w);
    return u;
}

// ---------------- Kernel 0: W -> WTf, MFMA-fragment order --------------------
// WTf fragment (kc, j): 64 lanes x 16B contiguous (1 KB). Element for lane:
// n = j*16 + (lane&15)  [0..63 K, 64..127 Q, 128..191 V],  k = kc*32 + (lane>>4)*8 + e.
__global__ __launch_bounds__(256) void prep_w(
        const float* __restrict__ Wk, const float* __restrict__ bk,
        const float* __restrict__ Wq, const float* __restrict__ bq,
        const float* __restrict__ Wv, const float* __restrict__ bv,
        unsigned short* __restrict__ WTf, float* __restrict__ biasb) {
    __shared__ float Wl[3][32][64];
    const int kc = blockIdx.x;               // 0..31
    const int tid = threadIdx.x;
    const float* Ws[3] = {Wk, Wq, Wv};
    const int row = tid >> 3, cf = (tid & 7) * 8;
    #pragma unroll
    for (int p = 0; p < 3; p++) {
        const float* W = Ws[p] + (long)(kc * 32 + row) * 64 + cf;
        float4 v0 = *(const float4*)(W);
        float4 v1 = *(const float4*)(W + 4);
        *(float4*)(&Wl[p][row][cf]) = v0;
        *(float4*)(&Wl[p][row][cf + 4]) = v1;
    }
    __syncthreads();
    #pragma unroll
    for (int i = 0; i < 3; i++) {
        int cid = i * 256 + tid;             // 0..767 = j*64 + lane
        int lane = cid & 63;
        int l15 = lane & 15, q4 = lane >> 4;
        int n = (cid >> 6) * 16 + l15;
        int p = n >> 6, col = n & 63;
        float scale = (p == 1) ? 0.03125f : 1.0f;   // fold C^-0.5 into q
        unsigned short o[8];
        for (int e = 0; e < 8; e++) o[e] = f2bf(Wl[p][q4 * 8 + e][col] * scale);
        *(int4*)(WTf + (long)kc * 6144 + (long)cid * 8) = *(int4*)o;
    }
    if (kc == 0 && tid < 192) {
        const float* bs[3] = {bk, bq, bv};
        int p = tid >> 6;
        biasb[tid] = bs[p][tid & 63] * ((p == 1) ? 0.03125f : 1.0f);
    }
}

// ---------------- Kernel 1: projections --------------------------------------
// grid 512 x 256thr (4 waves). Block = 32 rows. Phase 1: deep 32-load burst
// stages x-tile to LDS (one barrier total). Phase 2: zero-barrier K-loop,
// A from LDS, B via coalesced 1KB fragment loads (L2-hot).
__global__ __launch_bounds__(256) void proj_gemm(
        const float* __restrict__ x, const unsigned short* __restrict__ WTf,
        const float* __restrict__ biasb,
        unsigned short* __restrict__ Kb, unsigned short* __restrict__ Qb,
        unsigned short* __restrict__ VTb) {
    __shared__ __align__(16) unsigned short As[32 * 1032];

    const int tid = threadIdx.x;
    const int lane = tid & 63, w = tid >> 6;
    const int l15 = lane & 15, q4 = lane >> 4;
    const int mw = w & 1, nw = w >> 1;            // 2 row-halves x 2 col-halves
    const long rowbase = (long)blockIdx.x * 32;

    // ---- phase 1: 32 back-to-back float4 loads per thread, then cvt+LDS ----
    {
        const int r = tid >> 3, c0 = (tid & 7) * 4;
        const float* xr = x + (rowbase + r) * CEMB + c0;
        float4 buf[32];
        #pragma unroll
        for (int i = 0; i < 32; i++) buf[i] = *(const float4*)(xr + i * 32);
        unsigned short* lr = As + r * 1032 + c0;
        #pragma unroll
        for (int i = 0; i < 32; i++) *(ushort4*)(lr + i * 32) = f4bf(buf[i]);
    }
    __syncthreads();

    // ---- phase 2: K-loop, no barriers ----
    f32x4 z = {0.f, 0.f, 0.f, 0.f};
    f32x4 acc[6];
    for (int j = 0; j < 6; j++) acc[j] = z;

    const unsigned short* Am = As + (mw * 16 + l15) * 1032 + q4 * 8;
    const unsigned short* Bg = WTf + (long)(nw * 6) * 512 + (long)lane * 8;

    #pragma unroll 4
    for (int kc = 0; kc < 32; kc++) {
        bf16x8 a = *(const bf16x8*)(Am + kc * 32);
        bf16x8 bfr[6];
        #pragma unroll
        for (int j = 0; j < 6; j++)
            bfr[j] = *(const bf16x8*)(Bg + (long)kc * 6144 + j * 512);
        #pragma unroll
        for (int j = 0; j < 6; j++)
            acc[j] = __builtin_amdgcn_mfma_f32_16x16x32_bf16(a, bfr[j], acc[j], 0, 0, 0);
    }

    // ---- epilogue: +bias, cast bf16, scatter to K / Q / VT (validated) ----
    for (int j = 0; j < 6; j++) {
        const int n = nw * 96 + j * 16 + l15;
        const float bias = biasb[n];
        const long row0 = rowbase + mw * 16 + q4 * 4;
        if (n < 128) {
            unsigned short* dst = (n < 64) ? (Kb + row0 * HEAD + n)
                                           : (Qb + row0 * HEAD + (n - 64));
            for (int r = 0; r < 4; r++)
                dst[r * HEAD] = f2bf(acc[j][r] + bias);
        } else {
            const int h = n - 128;
            const long b = row0 >> 11; const int t = (int)(row0 & 2047);
            ushort4 pk;
            pk.x = f2bf(acc[j][0] + bias);
            pk.y = f2bf(acc[j][1] + bias);
            pk.z = f2bf(acc[j][2] + bias);
            pk.w = f2bf(acc[j][3] + bias);
            *(ushort4*)(VTb + b * (HEAD * (long)TSEQ) + (long)h * TSEQ + t) = pk;
        }
    }
}

// ---------------- Kernel 2: causal softplus-attention, Q/V prefetch ----------
// grid 512 = (64 t-tiles x 8 b), largest first. 4 waves split s-chunks; next
// chunk's Q/V fragments prefetched into registers during current chunk.
__global__ __launch_bounds__(256) void attn(
        const unsigned short* __restrict__ Kb, const unsigned short* __restrict__ Qb,
        const unsigned short* __restrict__ VTb, float* __restrict__ out) {
    __shared__ __align__(16) unsigned short Pl[4][2][32 * 40];
    __shared__ __align__(16) float red[3][64 * 36];

    const int tid = threadIdx.x;
    const int lane = tid & 63, w = tid >> 6;
    const int l15 = lane & 15, q4 = lane >> 4;

    const int bid = blockIdx.x;
    const int ti = 63 - (bid >> 3);             // largest t-tile first
    const int b = bid & 7;
    const int t0 = ti * 32;

    const unsigned short* kb  = Kb  + (long)b * TSEQ * HEAD;
    const unsigned short* qb  = Qb  + (long)b * TSEQ * HEAD;
    const unsigned short* vtb = VTb + (long)b * HEAD * TSEQ;

    // K fragments (fixed per block): B-operand, n = t-local, k = h
    bf16x8 kf[2][2];
    for (int tt = 0; tt < 2; tt++)
        for (int kk = 0; kk < 2; kk++)
            kf[tt][kk] = *(const bf16x8*)(kb + (t0 + tt * 16 + l15) * HEAD + kk * 32 + q4 * 8);

    f32x4 z = {0.f, 0.f, 0.f, 0.f};
    f32x4 oacc[4][2];
    for (int hh = 0; hh < 4; hh++) for (int tt = 0; tt < 2; tt++) oacc[hh][tt] = z;

    // prefetch registers for chunk c
    bf16x8 qpf[2][2], vpf[4];
    if (w <= ti) {
        const int s0 = w * 32;
        for (int st2 = 0; st2 < 2; st2++)
            for (int kk = 0; kk < 2; kk++)
                qpf[st2][kk] = *(const bf16x8*)(qb + (s0 + st2 * 16 + l15) * HEAD + kk * 32 + q4 * 8);
        for (int hh = 0; hh < 4; hh++)
            vpf[hh] = *(const bf16x8*)(vtb + (hh * 16 + l15) * (long)TSEQ + s0 + q4 * 8);
    }

    int buf = 0;
    for (int c = w; c <= ti; c += 4) {
        const int s0 = c * 32;
        unsigned short* myP = &Pl[w][buf][0];

        bf16x8 qf[2][2], vf[4];
        for (int st2 = 0; st2 < 2; st2++)
            for (int kk = 0; kk < 2; kk++) qf[st2][kk] = qpf[st2][kk];
        for (int hh = 0; hh < 4; hh++) vf[hh] = vpf[hh];

        // issue next chunk's Q/V loads now; they stay in flight across compute
        if (c + 4 <= ti) {
            const int sn = (c + 4) * 32;
            for (int st2 = 0; st2 < 2; st2++)
                for (int kk = 0; kk < 2; kk++)
                    qpf[st2][kk] = *(const bf16x8*)(qb + (sn + st2 * 16 + l15) * HEAD + kk * 32 + q4 * 8);
            for (int hh = 0; hh < 4; hh++)
                vpf[hh] = *(const bf16x8*)(vtb + (hh * 16 + l15) * (long)TSEQ + sn + q4 * 8);
        }

        // S^T = Q K^T: 2 s-tiles x 2 t-tiles
        f32x4 sc[2][2];
        for (int st2 = 0; st2 < 2; st2++)
            for (int tt = 0; tt < 2; tt++) {
                f32x4 s = z;
                s = __builtin_amdgcn_mfma_f32_16x16x32_bf16(qf[st2][0], kf[tt][0], s, 0, 0, 0);
                s = __builtin_amdgcn_mfma_f32_16x16x32_bf16(qf[st2][1], kf[tt][1], s, 0, 0, 0);
                sc[st2][tt] = s;
            }
        // softplus + causal mask; pack bf16 -> P^T LDS [t-local][s-local]
        for (int tt = 0; tt < 2; tt++) {
            const int tg = t0 + tt * 16 + l15;
            for (int st2 = 0; st2 < 2; st2++) {
                ushort4 pk;
                unsigned short pv[4];
                for (int r = 0; r < 4; r++) {
                    int sg = s0 + st2 * 16 + q4 * 4 + r;
                    float p = __logf(1.0f + __expf(sc[st2][tt][r]));
                    if (sg > tg) p = 0.0f;
                    pv[r] = f2bf(p);
                }
                pk.x = pv[0]; pk.y = pv[1]; pk.z = pv[2]; pk.w = pv[3];
                *(ushort4*)(myP + (tt * 16 + l15) * 40 + st2 * 16 + q4 * 4) = pk;
            }
        }
        __threadfence_block();
        bf16x8 pf0 = *(const bf16x8*)(myP + l15 * 40 + q4 * 8);
        bf16x8 pf1 = *(const bf16x8*)(myP + (16 + l15) * 40 + q4 * 8);
        for (int hh = 0; hh < 4; hh++) {
            oacc[hh][0] = __builtin_amdgcn_mfma_f32_16x16x32_bf16(vf[hh], pf0, oacc[hh][0], 0, 0, 0);
            oacc[hh][1] = __builtin_amdgcn_mfma_f32_16x16x32_bf16(vf[hh], pf1, oacc[hh][1], 0, 0, 0);
        }
        buf ^= 1;
    }

    // cross-wave reduction of O^T partials
    if (w > 0) {
        float* r0 = &red[w - 1][lane * 36];
        for (int hh = 0; hh < 4; hh++)
            for (int tt = 0; tt < 2; tt++)
                *(f32x4*)(r0 + (hh * 2 + tt) * 4) = oacc[hh][tt];
    }
    __syncthreads();
    if (w == 0) {
        for (int i = 0; i < 3; i++) {
            const float* r0 = &red[i][lane * 36];
            for (int hh = 0; hh < 4; hh++)
                for (int tt = 0; tt < 2; tt++)
                    oacc[hh][tt] += *(const f32x4*)(r0 + (hh * 2 + tt) * 4);
        }
        for (int tt = 0; tt < 2; tt++) {
            float* ob = out + ((long)b * TSEQ + t0 + tt * 16 + l15) * HEAD + q4 * 4;
            for (int hh = 0; hh < 4; hh++)
                *(f32x4*)(ob + hh * 16) = oacc[hh][tt];
        }
    }
}

// ---------------- host launch ------------------------------------------------
extern "C" void kernel_launch(void* const* d_in, const int* in_sizes, int n_in,
                              void* d_out, int out_size, void* d_ws, size_t ws_size,
                              hipStream_t stream) {
    const float* x  = (const float*)d_in[0];
    const float* Wk = (const float*)d_in[1];
    const float* bk = (const float*)d_in[2];
    const float* Wq = (const float*)d_in[3];
    const float* bq = (const float*)d_in[4];
    const float* Wv = (const float*)d_in[5];
    const float* bv = (const float*)d_in[6];
    float* out = (float*)d_out;

    char* ws = (char*)d_ws;
    unsigned short* WTf   = (unsigned short*)(ws);                      // 384 KB
    float*          biasb = (float*)(ws + 393216);                      // 768 B
    unsigned short* Kb    = (unsigned short*)(ws + 524288);             // 2 MB
    unsigned short* Qb    = (unsigned short*)(ws + 524288 + 2097152);   // 2 MB
    unsigned short* VTb   = (unsigned short*)(ws + 524288 + 4194304);   // 2 MB

    prep_w<<<32, 256, 0, stream>>>(Wk, bk, Wq, bq, Wv, bv, WTf, biasb);
    proj_gemm<<<512, 256, 0, stream>>>(x, WTf, biasb, Kb, Qb, VTb);
    attn<<<512, 256, 0, stream>>>(Kb, Qb, VTb, out);
}

// Round 5
// 145.988 us; speedup vs baseline: 1.3086x; 1.0511x over previous
//
#include <hip/hip_runtime.h>
#include <hip/hip_bf16.h>
#include <stdint.h>

#define HEAD 64
#define CEMB 1024
#define BB 8
#define TSEQ 2048

typedef __attribute__((ext_vector_type(8))) short bf16x8;
typedef __attribute__((ext_vector_type(4))) float f32x4;

__device__ __forceinline__ unsigned short f2bf(float f) {
    union { float f; uint32_t u; } c; c.f = f;
    uint32_t u = c.u + 0x7FFF + ((c.u >> 16) & 1);
    return (unsigned short)(u >> 16);
}
__device__ __forceinline__ ushort4 f4bf(float4 v) {
    ushort4 u; u.x = f2bf(v.x); u.y = f2bf(v.y); u.z = f2bf(v.z); u.w = f2bf(v.w);
    return u;
}

// ---------------- Kernel 0: W -> WTf, MFMA-fragment order (unchanged) --------
// Fragment (kc, j): 64 lanes x 16B contiguous (1 KB); n = j*16+(lane&15),
// k = kc*32 + (lane>>4)*8 + e.  j: 0-3 K, 4-7 Q(scaled), 8-11 V.
__global__ __launch_bounds__(256) void prep_w(
        const float* __restrict__ Wk, const float* __restrict__ bk,
        const float* __restrict__ Wq, const float* __restrict__ bq,
        const float* __restrict__ Wv, const float* __restrict__ bv,
        unsigned short* __restrict__ WTf, float* __restrict__ biasb) {
    __shared__ float Wl[3][32][64];
    const int kc = blockIdx.x;               // 0..31
    const int tid = threadIdx.x;
    const float* Ws[3] = {Wk, Wq, Wv};
    const int row = tid >> 3, cf = (tid & 7) * 8;
    #pragma unroll
    for (int p = 0; p < 3; p++) {
        const float* W = Ws[p] + (long)(kc * 32 + row) * 64 + cf;
        float4 v0 = *(const float4*)(W);
        float4 v1 = *(const float4*)(W + 4);
        *(float4*)(&Wl[p][row][cf]) = v0;
        *(float4*)(&Wl[p][row][cf + 4]) = v1;
    }
    __syncthreads();
    #pragma unroll
    for (int i = 0; i < 3; i++) {
        int cid = i * 256 + tid;             // 0..767 = j*64 + lane
        int lane = cid & 63;
        int l15 = lane & 15, q4 = lane >> 4;
        int n = (cid >> 6) * 16 + l15;
        int p = n >> 6, col = n & 63;
        float scale = (p == 1) ? 0.03125f : 1.0f;
        unsigned short o[8];
        for (int e = 0; e < 8; e++) o[e] = f2bf(Wl[p][q4 * 8 + e][col] * scale);
        *(int4*)(WTf + (long)kc * 6144 + (long)cid * 8) = *(int4*)o;
    }
    if (kc == 0 && tid < 192) {
        const float* bs[3] = {bk, bq, bv};
        int p = tid >> 6;
        biasb[tid] = bs[p][tid & 63] * ((p == 1) ? 0.03125f : 1.0f);
    }
}

// ---------------- Kernel 1: projections, register-resident B -----------------
// grid 256 x 768thr (12 waves, 1 block/CU). Wave j owns n-tile j: full-K
// B-stripe in 128 VGPRs (loaded once). A: 64 rows staged to LDS bf16 in 8
// BK=128 segments, software-pipelined (loads for s+1 in flight over MFMA s).
__global__ __launch_bounds__(768) void proj_gemm(
        const float* __restrict__ x, const unsigned short* __restrict__ WTf,
        const float* __restrict__ biasb,
        unsigned short* __restrict__ Kb, unsigned short* __restrict__ Qb,
        unsigned short* __restrict__ VTb) {
    __shared__ __align__(16) unsigned short As[64 * 1032];   // 132 KB

    const int tid = threadIdx.x;
    const int lane = tid & 63, w = tid >> 6;     // w = n-tile 0..11
    const int l15 = lane & 15, q4 = lane >> 4;
    const long rowbase = (long)blockIdx.x * 64;
    const float* xg = x + rowbase * CEMB;

    // ---- B: 32 coalesced 1KB fragment loads -> 128 VGPRs (L2-hot, once) ----
    bf16x8 Breg[32];
    {
        const unsigned short* Bg = WTf + w * 512 + (long)lane * 8;
        #pragma unroll
        for (int kc = 0; kc < 32; kc++)
            Breg[kc] = *(const bf16x8*)(Bg + (long)kc * 6144);
    }

    f32x4 z = {0.f, 0.f, 0.f, 0.f};
    f32x4 acc[4];
    #pragma unroll
    for (int m = 0; m < 4; m++) acc[m] = z;

    // ---- stage segment 0 (rows x k[0:128]) ----
    {
        #pragma unroll
        for (int it = 0; it < 3; it++) {
            int i = it * 768 + tid;
            if (i < 2048) {
                int row = i >> 5, c4 = (i & 31) * 4;
                float4 v = *(const float4*)(xg + row * CEMB + c4);
                *(ushort4*)(As + row * 1032 + c4) = f4bf(v);
            }
        }
    }
    __syncthreads();

    // ---- pipelined K-loop: 8 segments, fully unrolled (Breg stays static) --
    #pragma unroll
    for (int s = 0; s < 8; s++) {
        float4 pf[3];
        // issue seg s+1 loads (overlap compute below)
        if (s < 7) {
            #pragma unroll
            for (int it = 0; it < 3; it++) {
                int i = it * 768 + tid;
                if (i < 2048) {
                    int row = i >> 5, c4 = (i & 31) * 4;
                    pf[it] = *(const float4*)(xg + row * CEMB + (s + 1) * 128 + c4);
                }
            }
        }
        // compute seg s: 4 m-tiles x 4 kc, B from registers
        #pragma unroll
        for (int kc = 0; kc < 4; kc++) {
            const int kg = s * 4 + kc;
            #pragma unroll
            for (int m = 0; m < 4; m++) {
                bf16x8 a = *(const bf16x8*)(As + (m * 16 + l15) * 1032 + kg * 32 + q4 * 8);
                acc[m] = __builtin_amdgcn_mfma_f32_16x16x32_bf16(a, Breg[kg], acc[m], 0, 0, 0);
            }
        }
        // store seg s+1 (disjoint LDS region), then barrier
        if (s < 7) {
            #pragma unroll
            for (int it = 0; it < 3; it++) {
                int i = it * 768 + tid;
                if (i < 2048) {
                    int row = i >> 5, c4 = (i & 31) * 4;
                    *(ushort4*)(As + row * 1032 + (s + 1) * 128 + c4) = f4bf(pf[it]);
                }
            }
            __syncthreads();
        }
    }

    // ---- epilogue: +bias, cast bf16, per-wave scatter ----
    const int n = w * 16 + l15;
    const float bias = biasb[n];
    #pragma unroll
    for (int m = 0; m < 4; m++) {
        const long row0 = rowbase + m * 16 + q4 * 4;
        if (n < 128) {
            unsigned short* dst = (n < 64) ? (Kb + row0 * HEAD + n)
                                           : (Qb + row0 * HEAD + (n - 64));
            for (int r = 0; r < 4; r++)
                dst[r * HEAD] = f2bf(acc[m][r] + bias);
        } else {
            const int h = n - 128;
            const long b = row0 >> 11; const int t = (int)(row0 & 2047);
            ushort4 pk;
            pk.x = f2bf(acc[m][0] + bias);
            pk.y = f2bf(acc[m][1] + bias);
            pk.z = f2bf(acc[m][2] + bias);
            pk.w = f2bf(acc[m][3] + bias);
            *(ushort4*)(VTb + b * (HEAD * (long)TSEQ) + (long)h * TSEQ + t) = pk;
        }
    }
}

// ---------------- Kernel 2: causal softplus-attention (unchanged from R4) ----
__global__ __launch_bounds__(256) void attn(
        const unsigned short* __restrict__ Kb, const unsigned short* __restrict__ Qb,
        const unsigned short* __restrict__ VTb, float* __restrict__ out) {
    __shared__ __align__(16) unsigned short Pl[4][2][32 * 40];
    __shared__ __align__(16) float red[3][64 * 36];

    const int tid = threadIdx.x;
    const int lane = tid & 63, w = tid >> 6;
    const int l15 = lane & 15, q4 = lane >> 4;

    const int bid = blockIdx.x;
    const int ti = 63 - (bid >> 3);
    const int b = bid & 7;
    const int t0 = ti * 32;

    const unsigned short* kb  = Kb  + (long)b * TSEQ * HEAD;
    const unsigned short* qb  = Qb  + (long)b * TSEQ * HEAD;
    const unsigned short* vtb = VTb + (long)b * HEAD * TSEQ;

    bf16x8 kf[2][2];
    for (int tt = 0; tt < 2; tt++)
        for (int kk = 0; kk < 2; kk++)
            kf[tt][kk] = *(const bf16x8*)(kb + (t0 + tt * 16 + l15) * HEAD + kk * 32 + q4 * 8);

    f32x4 z = {0.f, 0.f, 0.f, 0.f};
    f32x4 oacc[4][2];
    for (int hh = 0; hh < 4; hh++) for (int tt = 0; tt < 2; tt++) oacc[hh][tt] = z;

    bf16x8 qpf[2][2], vpf[4];
    if (w <= ti) {
        const int s0 = w * 32;
        for (int st2 = 0; st2 < 2; st2++)
            for (int kk = 0; kk < 2; kk++)
                qpf[st2][kk] = *(const bf16x8*)(qb + (s0 + st2 * 16 + l15) * HEAD + kk * 32 + q4 * 8);
        for (int hh = 0; hh < 4; hh++)
            vpf[hh] = *(const bf16x8*)(vtb + (hh * 16 + l15) * (long)TSEQ + s0 + q4 * 8);
    }

    int buf = 0;
    for (int c = w; c <= ti; c += 4) {
        const int s0 = c * 32;
        unsigned short* myP = &Pl[w][buf][0];

        bf16x8 qf[2][2], vf[4];
        for (int st2 = 0; st2 < 2; st2++)
            for (int kk = 0; kk < 2; kk++) qf[st2][kk] = qpf[st2][kk];
        for (int hh = 0; hh < 4; hh++) vf[hh] = vpf[hh];

        if (c + 4 <= ti) {
            const int sn = (c + 4) * 32;
            for (int st2 = 0; st2 < 2; st2++)
                for (int kk = 0; kk < 2; kk++)
                    qpf[st2][kk] = *(const bf16x8*)(qb + (sn + st2 * 16 + l15) * HEAD + kk * 32 + q4 * 8);
            for (int hh = 0; hh < 4; hh++)
                vpf[hh] = *(const bf16x8*)(vtb + (hh * 16 + l15) * (long)TSEQ + sn + q4 * 8);
        }

        f32x4 sc[2][2];
        for (int st2 = 0; st2 < 2; st2++)
            for (int tt = 0; tt < 2; tt++) {
                f32x4 s = z;
                s = __builtin_amdgcn_mfma_f32_16x16x32_bf16(qf[st2][0], kf[tt][0], s, 0, 0, 0);
                s = __builtin_amdgcn_mfma_f32_16x16x32_bf16(qf[st2][1], kf[tt][1], s, 0, 0, 0);
                sc[st2][tt] = s;
            }
        for (int tt = 0; tt < 2; tt++) {
            const int tg = t0 + tt * 16 + l15;
            for (int st2 = 0; st2 < 2; st2++) {
                ushort4 pk;
                unsigned short pv[4];
                for (int r = 0; r < 4; r++) {
                    int sg = s0 + st2 * 16 + q4 * 4 + r;
                    float p = __logf(1.0f + __expf(sc[st2][tt][r]));
                    if (sg > tg) p = 0.0f;
                    pv[r] = f2bf(p);
                }
                pk.x = pv[0]; pk.y = pv[1]; pk.z = pv[2]; pk.w = pv[3];
                *(ushort4*)(myP + (tt * 16 + l15) * 40 + st2 * 16 + q4 * 4) = pk;
            }
        }
        __threadfence_block();
        bf16x8 pf0 = *(const bf16x8*)(myP + l15 * 40 + q4 * 8);
        bf16x8 pf1 = *(const bf16x8*)(myP + (16 + l15) * 40 + q4 * 8);
        for (int hh = 0; hh < 4; hh++) {
            oacc[hh][0] = __builtin_amdgcn_mfma_f32_16x16x32_bf16(vf[hh], pf0, oacc[hh][0], 0, 0, 0);
            oacc[hh][1] = __builtin_amdgcn_mfma_f32_16x16x32_bf16(vf[hh], pf1, oacc[hh][1], 0, 0, 0);
        }
        buf ^= 1;
    }

    if (w > 0) {
        float* r0 = &red[w - 1][lane * 36];
        for (int hh = 0; hh < 4; hh++)
            for (int tt = 0; tt < 2; tt++)
                *(f32x4*)(r0 + (hh * 2 + tt) * 4) = oacc[hh][tt];
    }
    __syncthreads();
    if (w == 0) {
        for (int i = 0; i < 3; i++) {
            const float* r0 = &red[i][lane * 36];
            for (int hh = 0; hh < 4; hh++)
                for (int tt = 0; tt < 2; tt++)
                    oacc[hh][tt] += *(const f32x4*)(r0 + (hh * 2 + tt) * 4);
        }
        for (int tt = 0; tt < 2; tt++) {
            float* ob = out + ((long)b * TSEQ + t0 + tt * 16 + l15) * HEAD + q4 * 4;
            for (int hh = 0; hh < 4; hh++)
                *(f32x4*)(ob + hh * 16) = oacc[hh][tt];
        }
    }
}

// ---------------- host launch ------------------------------------------------
extern "C" void kernel_launch(void* const* d_in, const int* in_sizes, int n_in,
                              void* d_out, int out_size, void* d_ws, size_t ws_size,
                              hipStream_t stream) {
    const float* x  = (const float*)d_in[0];
    const float* Wk = (const float*)d_in[1];
    const float* bk = (const float*)d_in[2];
    const float* Wq = (const float*)d_in[3];
    const float* bq = (const float*)d_in[4];
    const float* Wv = (const float*)d_in[5];
    const float* bv = (const float*)d_in[6];
    float* out = (float*)d_out;

    char* ws = (char*)d_ws;
    unsigned short* WTf   = (unsigned short*)(ws);                      // 384 KB
    float*          biasb = (float*)(ws + 393216);                      // 768 B
    unsigned short* Kb    = (unsigned short*)(ws + 524288);             // 2 MB
    unsigned short* Qb    = (unsigned short*)(ws + 524288 + 2097152);   // 2 MB
    unsigned short* VTb   = (unsigned short*)(ws + 524288 + 4194304);   // 2 MB

    prep_w<<<32, 256, 0, stream>>>(Wk, bk, Wq, bq, Wv, bv, WTf, biasb);
    proj_gemm<<<256, 768, 0, stream>>>(x, WTf, biasb, Kb, Qb, VTb);
    attn<<<512, 256, 0, stream>>>(Kb, Qb, VTb, out);
}

// Round 6
// 141.968 us; speedup vs baseline: 1.3457x; 1.0283x over previous
//
#include <hip/hip_runtime.h>
#include <hip/hip_bf16.h>
#include <stdint.h>

#define HEAD 64
#define CEMB 1024
#define BB 8
#define TSEQ 2048

typedef __attribute__((ext_vector_type(8))) short bf16x8;
typedef __attribute__((ext_vector_type(4))) float f32x4;

__device__ __forceinline__ unsigned short f2bf(float f) {
    union { float f; uint32_t u; } c; c.f = f;
    uint32_t u = c.u + 0x7FFF + ((c.u >> 16) & 1);
    return (unsigned short)(u >> 16);
}
__device__ __forceinline__ ushort4 f4bf(float4 v) {
    ushort4 u; u.x = f2bf(v.x); u.y = f2bf(v.y); u.z = f2bf(v.z); u.w = f2bf(v.w);
    return u;
}

// ---------------- Kernel 0: W -> WTf, MFMA-fragment order (unchanged) --------
// Fragment (kc, j): 64 lanes x 16B contiguous (1 KB); n = j*16+(lane&15),
// k = kc*32 + (lane>>4)*8 + e.  j: 0-3 K, 4-7 Q(scaled), 8-11 V.
__global__ __launch_bounds__(256) void prep_w(
        const float* __restrict__ Wk, const float* __restrict__ bk,
        const float* __restrict__ Wq, const float* __restrict__ bq,
        const float* __restrict__ Wv, const float* __restrict__ bv,
        unsigned short* __restrict__ WTf, float* __restrict__ biasb) {
    __shared__ float Wl[3][32][64];
    const int kc = blockIdx.x;               // 0..31
    const int tid = threadIdx.x;
    const float* Ws[3] = {Wk, Wq, Wv};
    const int row = tid >> 3, cf = (tid & 7) * 8;
    #pragma unroll
    for (int p = 0; p < 3; p++) {
        const float* W = Ws[p] + (long)(kc * 32 + row) * 64 + cf;
        float4 v0 = *(const float4*)(W);
        float4 v1 = *(const float4*)(W + 4);
        *(float4*)(&Wl[p][row][cf]) = v0;
        *(float4*)(&Wl[p][row][cf + 4]) = v1;
    }
    __syncthreads();
    #pragma unroll
    for (int i = 0; i < 3; i++) {
        int cid = i * 256 + tid;             // 0..767 = j*64 + lane
        int lane = cid & 63;
        int l15 = lane & 15, q4 = lane >> 4;
        int n = (cid >> 6) * 16 + l15;
        int p = n >> 6, col = n & 63;
        float scale = (p == 1) ? 0.03125f : 1.0f;
        unsigned short o[8];
        for (int e = 0; e < 8; e++) o[e] = f2bf(Wl[p][q4 * 8 + e][col] * scale);
        *(int4*)(WTf + (long)kc * 6144 + (long)cid * 8) = *(int4*)o;
    }
    if (kc == 0 && tid < 192) {
        const float* bs[3] = {bk, bq, bv};
        int p = tid >> 6;
        biasb[tid] = bs[p][tid & 63] * ((p == 1) ? 0.03125f : 1.0f);
    }
}

// ---------------- Kernel 1: projections, register-resident B (half-K) --------
// grid 256 x 768thr (12 waves, 1 block/CU). Wave j owns n-tile j. B-stripe
// held HALF-K at a time: Breg[16] = 64 VGPRs (reloaded once, L2-hot) so the
// wave fits the 168-VGPR cap at 3 waves/EU -- R5's Breg[32] spilled (VGPR=84).
__global__ __launch_bounds__(768) void proj_gemm(
        const float* __restrict__ x, const unsigned short* __restrict__ WTf,
        const float* __restrict__ biasb,
        unsigned short* __restrict__ Kb, unsigned short* __restrict__ Qb,
        unsigned short* __restrict__ VTb) {
    __shared__ __align__(16) unsigned short As[64 * 1032];   // 132 KB

    const int tid = threadIdx.x;
    const int lane = tid & 63, w = tid >> 6;     // w = n-tile 0..11
    const int l15 = lane & 15, q4 = lane >> 4;
    const long rowbase = (long)blockIdx.x * 64;
    const float* xg = x + rowbase * CEMB;
    const unsigned short* Bg = WTf + w * 512 + (long)lane * 8;

    f32x4 z = {0.f, 0.f, 0.f, 0.f};
    f32x4 acc[4];
    #pragma unroll
    for (int m = 0; m < 4; m++) acc[m] = z;

    bf16x8 Breg[16];

    // ---- stage segment 0 (rows x k[0:128]) ----
    {
        #pragma unroll
        for (int it = 0; it < 3; it++) {
            int i = it * 768 + tid;
            if (i < 2048) {
                int row = i >> 5, c4 = (i & 31) * 4;
                float4 v = *(const float4*)(xg + row * CEMB + c4);
                *(ushort4*)(As + row * 1032 + c4) = f4bf(v);
            }
        }
    }
    __syncthreads();

    // ---- pipelined K-loop: 2 halves x 4 segments ----
    #pragma unroll
    for (int half = 0; half < 2; half++) {
        // load this half's 16 B-fragments (64 VGPRs; L2-hot 1KB coalesced)
        #pragma unroll
        for (int i = 0; i < 16; i++)
            Breg[i] = *(const bf16x8*)(Bg + (long)(half * 16 + i) * 6144);

        #pragma unroll
        for (int ss = 0; ss < 4; ss++) {
            const int s = half * 4 + ss;
            float4 pf[3];
            // issue seg s+1 global loads (in flight across MFMA below)
            if (s < 7) {
                #pragma unroll
                for (int it = 0; it < 3; it++) {
                    int i = it * 768 + tid;
                    if (i < 2048) {
                        int row = i >> 5, c4 = (i & 31) * 4;
                        pf[it] = *(const float4*)(xg + row * CEMB + (s + 1) * 128 + c4);
                    }
                }
            }
            // compute seg s: 4 kc x 4 m-tiles, B from registers
            #pragma unroll
            for (int kc = 0; kc < 4; kc++) {
                const int kg = s * 4 + kc;
                #pragma unroll
                for (int m = 0; m < 4; m++) {
                    bf16x8 a = *(const bf16x8*)(As + (m * 16 + l15) * 1032 + kg * 32 + q4 * 8);
                    acc[m] = __builtin_amdgcn_mfma_f32_16x16x32_bf16(a, Breg[ss * 4 + kc], acc[m], 0, 0, 0);
                }
            }
            // store seg s+1 (disjoint LDS region), then barrier
            if (s < 7) {
                #pragma unroll
                for (int it = 0; it < 3; it++) {
                    int i = it * 768 + tid;
                    if (i < 2048) {
                        int row = i >> 5, c4 = (i & 31) * 4;
                        *(ushort4*)(As + row * 1032 + (s + 1) * 128 + c4) = f4bf(pf[it]);
                    }
                }
                __syncthreads();
            }
        }
    }

    // ---- epilogue: +bias, cast bf16, per-wave scatter ----
    const int n = w * 16 + l15;
    const float bias = biasb[n];
    #pragma unroll
    for (int m = 0; m < 4; m++) {
        const long row0 = rowbase + m * 16 + q4 * 4;
        if (n < 128) {
            unsigned short* dst = (n < 64) ? (Kb + row0 * HEAD + n)
                                           : (Qb + row0 * HEAD + (n - 64));
            for (int r = 0; r < 4; r++)
                dst[r * HEAD] = f2bf(acc[m][r] + bias);
        } else {
            const int h = n - 128;
            const long b = row0 >> 11; const int t = (int)(row0 & 2047);
            ushort4 pk;
            pk.x = f2bf(acc[m][0] + bias);
            pk.y = f2bf(acc[m][1] + bias);
            pk.z = f2bf(acc[m][2] + bias);
            pk.w = f2bf(acc[m][3] + bias);
            *(ushort4*)(VTb + b * (HEAD * (long)TSEQ) + (long)h * TSEQ + t) = pk;
        }
    }
}

// ---------------- Kernel 2: causal softplus-attention, 8 waves ---------------
// grid 512 x 512thr. 8 waves split s-chunks; P-scratch and tree-reduction
// regions share one 37 KB LDS union -> 2 blocks/CU, 16 waves/CU.
__global__ __launch_bounds__(512) void attn(
        const unsigned short* __restrict__ Kb, const unsigned short* __restrict__ Qb,
        const unsigned short* __restrict__ VTb, float* __restrict__ out) {
    __shared__ __align__(16) char sm[36864];   // max(Pl 20480, red 36864)
    unsigned short* Pl = (unsigned short*)sm;  // [8 waves][32*40]
    float* red = (float*)sm;                   // [4][64*36]

    const int tid = threadIdx.x;
    const int lane = tid & 63, w = tid >> 6;   // 8 waves
    const int l15 = lane & 15, q4 = lane >> 4;

    const int bid = blockIdx.x;
    const int ti = 63 - (bid >> 3);            // largest t-tile first
    const int b = bid & 7;
    const int t0 = ti * 32;

    const unsigned short* kb  = Kb  + (long)b * TSEQ * HEAD;
    const unsigned short* qb  = Qb  + (long)b * TSEQ * HEAD;
    const unsigned short* vtb = VTb + (long)b * HEAD * TSEQ;

    bf16x8 kf[2][2];
    for (int tt = 0; tt < 2; tt++)
        for (int kk = 0; kk < 2; kk++)
            kf[tt][kk] = *(const bf16x8*)(kb + (t0 + tt * 16 + l15) * HEAD + kk * 32 + q4 * 8);

    f32x4 z = {0.f, 0.f, 0.f, 0.f};
    f32x4 oacc[4][2];
    for (int hh = 0; hh < 4; hh++) for (int tt = 0; tt < 2; tt++) oacc[hh][tt] = z;

    bf16x8 qpf[2][2], vpf[4];
    if (w <= ti) {
        const int s0 = w * 32;
        for (int st2 = 0; st2 < 2; st2++)
            for (int kk = 0; kk < 2; kk++)
                qpf[st2][kk] = *(const bf16x8*)(qb + (s0 + st2 * 16 + l15) * HEAD + kk * 32 + q4 * 8);
        for (int hh = 0; hh < 4; hh++)
            vpf[hh] = *(const bf16x8*)(vtb + (hh * 16 + l15) * (long)TSEQ + s0 + q4 * 8);
    }

    unsigned short* myP = Pl + w * 1280;
    for (int c = w; c <= ti; c += 8) {
        const int s0 = c * 32;

        bf16x8 qf[2][2], vf[4];
        for (int st2 = 0; st2 < 2; st2++)
            for (int kk = 0; kk < 2; kk++) qf[st2][kk] = qpf[st2][kk];
        for (int hh = 0; hh < 4; hh++) vf[hh] = vpf[hh];

        if (c + 8 <= ti) {
            const int sn = (c + 8) * 32;
            for (int st2 = 0; st2 < 2; st2++)
                for (int kk = 0; kk < 2; kk++)
                    qpf[st2][kk] = *(const bf16x8*)(qb + (sn + st2 * 16 + l15) * HEAD + kk * 32 + q4 * 8);
            for (int hh = 0; hh < 4; hh++)
                vpf[hh] = *(const bf16x8*)(vtb + (hh * 16 + l15) * (long)TSEQ + sn + q4 * 8);
        }

        // S^T = Q K^T: 2 s-tiles x 2 t-tiles
        f32x4 sc[2][2];
        for (int st2 = 0; st2 < 2; st2++)
            for (int tt = 0; tt < 2; tt++) {
                f32x4 s = z;
                s = __builtin_amdgcn_mfma_f32_16x16x32_bf16(qf[st2][0], kf[tt][0], s, 0, 0, 0);
                s = __builtin_amdgcn_mfma_f32_16x16x32_bf16(qf[st2][1], kf[tt][1], s, 0, 0, 0);
                sc[st2][tt] = s;
            }
        // softplus + causal mask; pack bf16 -> P^T LDS [t-local][s-local]
        for (int tt = 0; tt < 2; tt++) {
            const int tg = t0 + tt * 16 + l15;
            for (int st2 = 0; st2 < 2; st2++) {
                ushort4 pk;
                unsigned short pv[4];
                for (int r = 0; r < 4; r++) {
                    int sg = s0 + st2 * 16 + q4 * 4 + r;
                    float p = __logf(1.0f + __expf(sc[st2][tt][r]));
                    if (sg > tg) p = 0.0f;
                    pv[r] = f2bf(p);
                }
                pk.x = pv[0]; pk.y = pv[1]; pk.z = pv[2]; pk.w = pv[3];
                *(ushort4*)(myP + (tt * 16 + l15) * 40 + st2 * 16 + q4 * 4) = pk;
            }
        }
        __threadfence_block();
        bf16x8 pf0 = *(const bf16x8*)(myP + l15 * 40 + q4 * 8);
        bf16x8 pf1 = *(const bf16x8*)(myP + (16 + l15) * 40 + q4 * 8);
        for (int hh = 0; hh < 4; hh++) {
            oacc[hh][0] = __builtin_amdgcn_mfma_f32_16x16x32_bf16(vf[hh], pf0, oacc[hh][0], 0, 0, 0);
            oacc[hh][1] = __builtin_amdgcn_mfma_f32_16x16x32_bf16(vf[hh], pf1, oacc[hh][1], 0, 0, 0);
        }
    }

    // ---- 3-stage tree reduction over 8 waves (red unions Pl; synced) ----
    __syncthreads();                           // all Pl use done
    if (w >= 4) {
        float* r0 = red + (w - 4) * 2304 + lane * 36;
        for (int hh = 0; hh < 4; hh++)
            for (int tt = 0; tt < 2; tt++)
                *(f32x4*)(r0 + (hh * 2 + tt) * 4) = oacc[hh][tt];
    }
    __syncthreads();
    if (w < 4) {
        const float* r0 = red + w * 2304 + lane * 36;
        for (int hh = 0; hh < 4; hh++)
            for (int tt = 0; tt < 2; tt++)
                oacc[hh][tt] += *(const f32x4*)(r0 + (hh * 2 + tt) * 4);
    }
    __syncthreads();
    if (w == 2 || w == 3) {
        float* r0 = red + (w - 2) * 2304 + lane * 36;
        for (int hh = 0; hh < 4; hh++)
            for (int tt = 0; tt < 2; tt++)
                *(f32x4*)(r0 + (hh * 2 + tt) * 4) = oacc[hh][tt];
    }
    __syncthreads();
    if (w < 2) {
        const float* r0 = red + w * 2304 + lane * 36;
        for (int hh = 0; hh < 4; hh++)
            for (int tt = 0; tt < 2; tt++)
                oacc[hh][tt] += *(const f32x4*)(r0 + (hh * 2 + tt) * 4);
    }
    __syncthreads();
    if (w == 1) {
        float* r0 = red + lane * 36;
        for (int hh = 0; hh < 4; hh++)
            for (int tt = 0; tt < 2; tt++)
                *(f32x4*)(r0 + (hh * 2 + tt) * 4) = oacc[hh][tt];
    }
    __syncthreads();
    if (w == 0) {
        const float* r0 = red + lane * 36;
        for (int hh = 0; hh < 4; hh++)
            for (int tt = 0; tt < 2; tt++)
                oacc[hh][tt] += *(const f32x4*)(r0 + (hh * 2 + tt) * 4);
        for (int tt = 0; tt < 2; tt++) {
            float* ob = out + ((long)b * TSEQ + t0 + tt * 16 + l15) * HEAD + q4 * 4;
            for (int hh = 0; hh < 4; hh++)
                *(f32x4*)(ob + hh * 16) = oacc[hh][tt];
        }
    }
}

// ---------------- host launch ------------------------------------------------
extern "C" void kernel_launch(void* const* d_in, const int* in_sizes, int n_in,
                              void* d_out, int out_size, void* d_ws, size_t ws_size,
                              hipStream_t stream) {
    const float* x  = (const float*)d_in[0];
    const float* Wk = (const float*)d_in[1];
    const float* bk = (const float*)d_in[2];
    const float* Wq = (const float*)d_in[3];
    const float* bq = (const float*)d_in[4];
    const float* Wv = (const float*)d_in[5];
    const float* bv = (const float*)d_in[6];
    float* out = (float*)d_out;

    char* ws = (char*)d_ws;
    unsigned short* WTf   = (unsigned short*)(ws);                      // 384 KB
    float*          biasb = (float*)(ws + 393216);                      // 768 B
    unsigned short* Kb    = (unsigned short*)(ws + 524288);             // 2 MB
    unsigned short* Qb    = (unsigned short*)(ws + 524288 + 2097152);   // 2 MB
    unsigned short* VTb   = (unsigned short*)(ws + 524288 + 4194304);   // 2 MB

    prep_w<<<32, 256, 0, stream>>>(Wk, bk, Wq, bq, Wv, bv, WTf, biasb);
    proj_gemm<<<256, 768, 0, stream>>>(x, WTf, biasb, Kb, Qb, VTb);
    attn<<<512, 512, 0, stream>>>(Kb, Qb, VTb, out);
}